// Round 2
// baseline (808.084 us; speedup 1.0000x reference)
//
#include <hip/hip_runtime.h>
#include <stdint.h>

typedef __attribute__((ext_vector_type(8))) short bf16x8;
typedef __attribute__((ext_vector_type(4))) float f32x4;

static constexpr int MNBR   = 12;
static constexpr int AF     = 64;     // atom feature dim
static constexpr int EF     = 41;     // edge feature dim
static constexpr int IN_DIM = 2 * AF + EF;   // 169
static constexpr float BN_EPS = 1e-5f;

// LDS EW tile: 16 rows x 128 ch, row stride 132 u16 (=66 dwords, breaks
// power-of-2 bank strides; all access 2-way conflict max = free)
static constexpr int EW_ROW_U16 = 132;

__device__ __forceinline__ uint16_t f2bfbits(float f) {
    uint32_t x = __float_as_uint(f);
    uint32_t r = x + 0x7fffu + ((x >> 16) & 1u);  // RNE
    return (uint16_t)(r >> 16);
}
__device__ __forceinline__ float softplusf(float x) {
    return fmaxf(x, 0.f) + __logf(1.0f + __expf(-fabsf(x)));
}

// ---------------------------------------------------------------------------
// K0: repack fc_w (fp32) into bf16 MFMA B-fragment order.
// B frag for 16x16x32: lane holds B[k = s*32 + (lane>>4)*8 + j][n = lane&15].
__global__ __launch_bounds__(256) void k_prep(
    const float* __restrict__ fc_w, uint16_t* __restrict__ wp_proj,
    uint16_t* __restrict__ wp_edge)
{
    int e = blockIdx.x * 256 + threadIdx.x;
    if (e < 16384) {
        int j = e & 7, lane = (e >> 3) & 63, s = (e >> 9) & 1, t = e >> 10;
        int n = lane & 15, q = lane >> 4;
        int k = s * 32 + q * 8 + j;
        int c = t * 16 + n;
        float v = (c < 128) ? fc_w[c * IN_DIM + k]
                            : fc_w[(c - 128) * IN_DIM + 64 + k];
        wp_proj[e] = f2bfbits(v);
    } else if (e < 24576) {
        int e2 = e - 16384;
        int j = e2 & 7, lane = (e2 >> 3) & 63, s = (e2 >> 9) & 1, t = e2 >> 10;
        int n = lane & 15, q = lane >> 4;
        int k = s * 32 + q * 8 + j;
        int o = t * 16 + n;
        wp_edge[e2] = (k < EF) ? f2bfbits(fc_w[o * IN_DIM + 2 * AF + k])
                               : (uint16_t)0;
    }
}

// ---------------------------------------------------------------------------
// K1 (MFMA): projection GEMM. Output is PAIR-INTERLEAVED:
//   Ps[n][o] u32 = { lo: self ch o (+bias[o]), hi: self ch 64+o (+bias[64+o]) }
//   Pn[n][o] u32 = { lo: nbr  ch o,            hi: nbr  ch 64+o }
// so the conv epilogue gathers ONE dword per edge per lane.
__global__ __launch_bounds__(256) void k_proj(
    const float* __restrict__ atom_in, const uint16_t* __restrict__ wp_proj,
    const float* __restrict__ fc_b, uint16_t* __restrict__ Ps,
    uint16_t* __restrict__ Pn, int N)
{
    const int lane = threadIdx.x & 63;
    const int w    = __builtin_amdgcn_readfirstlane((int)(threadIdx.x >> 6));
    const int a0   = blockIdx.x * 64 + w * 16;
    const int mrow = lane & 15, q = lane >> 4;
    const int arow = a0 + mrow;

    bf16x8 A0 = {}, A1 = {};
    if (arow < N) {
        const float* pa = atom_in + (size_t)arow * AF;
#pragma unroll
        for (int j = 0; j < 8; ++j) {
            A0[j] = (short)f2bfbits(pa[q * 8 + j]);       // k = q*8+j
            A1[j] = (short)f2bfbits(pa[32 + q * 8 + j]);  // k = 32+q*8+j
        }
    }

    const bf16x8* wp = (const bf16x8*)wp_proj;
#pragma unroll
    for (int t = 0; t < 16; ++t) {
        f32x4 acc = {0.f, 0.f, 0.f, 0.f};
        bf16x8 b0 = wp[(t * 2 + 0) * 64 + lane];
        bf16x8 b1 = wp[(t * 2 + 1) * 64 + lane];
        acc = __builtin_amdgcn_mfma_f32_16x16x32_bf16(A0, b0, acc, 0, 0, 0);
        acc = __builtin_amdgcn_mfma_f32_16x16x32_bf16(A1, b1, acc, 0, 0, 0);
        const int c = t * 16 + (lane & 15);               // C col = channel
        const float bias = (c < 128) ? fc_b[c] : 0.f;
#pragma unroll
        for (int r = 0; r < 4; ++r) {
            const int row = q * 4 + r;                    // C row = atom
            const int atom = a0 + row;
            if (atom < N) {
                const uint16_t v = f2bfbits(acc[r] + bias);
                const size_t base = (size_t)atom * 128;
                if (c < 64)       Ps[base + 2 * c] = v;
                else if (c < 128) Ps[base + 2 * (c - 64) + 1] = v;
                else if (c < 192) Pn[base + 2 * (c - 128)] = v;
                else              Pn[base + 2 * (c - 192) + 1] = v;
            }
        }
    }
}

// ---------------------------------------------------------------------------
// K2/K4: fused conv pass. Block = 384 edge rows = 32 atoms. Wave = 96 rows.
// Round-2 fixes (vs round-1 scratch catastrophe):
//  * NO lambda, NO runtime-indexed arrays. pnv[16] lives inside the tile
//    loop and is only indexed by inner-unrolled constants -> registers.
//  * self-pair loads per tile go into two NAMED regs (psA/psB), pre-issued
//    at tile top so their latency hides under the GEMM; epilogue selects
//    with a toggling bool (no psv[g/12] array indexing).
//  * edge rows loaded directly at tile top (round-0 pattern, proven).
//  * neighbor indices preloaded to 2 VGPRs, fetched via v_readlane.
//  * Pn gathers: 1 dword/lane/edge (pair layout), issued BEFORE the
//    GEMM+transpose+barrier (in flight across the barrier drain).
//  * edge-weight B fragments staged once in LDS (16KB) -> low VGPR.
template <int MODE>
__global__ __launch_bounds__(256, 3) void k_conv(
    const uint32_t* __restrict__ Ps32, const uint32_t* __restrict__ Pn32,
    const float* __restrict__ nbr, const int* __restrict__ idx,
    const uint16_t* __restrict__ wp_edge, const float* __restrict__ bn1coef,
    float* __restrict__ partial, float* __restrict__ nsum, int N)
{
    __shared__ uint16_t ew16[4][16 * EW_ROW_U16];
    __shared__ float red[4][256];
    __shared__ uint16_t bsh[8192];          // staged wp_edge (16 KB)

    const int tid  = threadIdx.x;
    const int lane = tid & 63;
    const int w    = __builtin_amdgcn_readfirstlane((int)(tid >> 6));
    const int col  = lane & 15, q = lane >> 4;
    const int o    = lane;                  // epilogue channel pair (o, o+64)
    (void)N;

    const int rbase = blockIdx.x * 384 + w * 96;   // divisible by 12
    const int nbase = rbase / 12;

    // ---- preload neighbor indices for this wave's 96 rows (2 VGPRs)
    int idxA = idx[rbase + lane];
    int idxB = 0;
    if (lane < 32) idxB = idx[rbase + 64 + lane];

    // ---- stage edge-weight B fragments into LDS (shared by all 4 waves)
    {
        const uint4* s4 = (const uint4*)wp_edge;
        uint4* d4 = (uint4*)bsh;
#pragma unroll
        for (int k = 0; k < 4; ++k) d4[k * 256 + tid] = s4[k * 256 + tid];
    }

    float s1f = 0.f, h1f = 0.f, s1c = 0.f, h1c = 0.f;
    if (MODE == 1) {
        s1f = bn1coef[o];       h1f = bn1coef[128 + o];
        s1c = bn1coef[64 + o];  h1c = bn1coef[192 + o];
    }

    float sA = 0.f, qA = 0.f, sB = 0.f, qB = 0.f;
    float accm = 0.f, psf = 0.f, psc = 0.f;
    uint16_t* myew = ew16[w];
    const bf16x8* bvs = (const bf16x8*)bsh;

    __syncthreads();   // bsh staged before first GEMM use

#pragma unroll
    for (int mt = 0; mt < 6; ++mt) {
        const int rs = rbase + mt * 16;

        // ---- issue this tile's 16 neighbor gathers (consumed after barrier)
        uint32_t pnv[16];
#pragma unroll
        for (int i = 0; i < 16; ++i) {
            const int g = mt * 16 + i;
            const int j = (g < 64) ? __builtin_amdgcn_readlane(idxA, g)
                                   : __builtin_amdgcn_readlane(idxB, g - 64);
            pnv[i] = Pn32[(size_t)j * 64 + o];
        }

        // ---- pre-issue the (<=2) self-pair loads whose m==0 row is in this
        // tile. Named regs, uniform guards — never an indexed array.
        const int aA = (mt * 16 + 11) / 12;     // first atom starting in tile
        const int gA = aA * 12;
        const int gB = gA + 12;
        uint32_t psA = 0u, psB = 0u;
        if (gA < mt * 16 + 16) psA = Ps32[(size_t)(nbase + aA) * 64 + o];
        if (gB < mt * 16 + 16) psB = Ps32[(size_t)(nbase + aA + 1) * 64 + o];
        bool useB = false;

        // ---- A fragments: fp32 edge row -> bf16 on the fly
        const float* er = nbr + (size_t)(rs + col) * EF;
        bf16x8 A0, A1 = {};
#pragma unroll
        for (int j = 0; j < 8; ++j) A0[j] = (short)f2bfbits(er[q * 8 + j]);
        if (q == 0) {
#pragma unroll
            for (int j = 0; j < 8; ++j) A1[j] = (short)f2bfbits(er[32 + j]);
        } else if (q == 1) {
            A1[0] = (short)f2bfbits(er[40]);
        }

        // ---- edge GEMM: 8 N-tiles, B from LDS
        f32x4 acc[8];
#pragma unroll
        for (int t = 0; t < 8; ++t) {
            bf16x8 b0 = bvs[(t * 2 + 0) * 64 + lane];
            bf16x8 b1 = bvs[(t * 2 + 1) * 64 + lane];
            f32x4 a = {0.f, 0.f, 0.f, 0.f};
            a = __builtin_amdgcn_mfma_f32_16x16x32_bf16(A0, b0, a, 0, 0, 0);
            a = __builtin_amdgcn_mfma_f32_16x16x32_bf16(A1, b1, a, 0, 0, 0);
            acc[t] = a;
        }

        // ---- C -> LDS, interleaved: ch<64 at even u16, ch>=64 at odd u16
#pragma unroll
        for (int t = 0; t < 8; ++t) {
            const int ch  = t * 16 + col;
            const int pos = (ch < 64) ? (ch * 2) : ((ch - 64) * 2 + 1);
#pragma unroll
            for (int r = 0; r < 4; ++r) {
                const int row = q * 4 + r;
                myew[row * EW_ROW_U16 + pos] = f2bfbits(acc[t][r]);
            }
        }
        __syncthreads();   // writes (all lanes) visible before cross-lane reads

        // ---- epilogue: 16 rows, lane o handles channels (o, o+64)
#pragma unroll
        for (int i = 0; i < 16; ++i) {
            const int g = mt * 16 + i;
            const int m = g % 12;
            if (m == 0) {
                const uint32_t pp = useB ? psB : psA;
                useB = true;
                psf  = __uint_as_float(pp << 16);          // includes bias[o]
                psc  = __uint_as_float(pp & 0xffff0000u);  // includes bias[o+64]
                accm = 0.f;
            }
            uint32_t pr;
            __builtin_memcpy(&pr, &myew[i * EW_ROW_U16 + 2 * o], 4);
            const float ewf = __uint_as_float(pr << 16);          // ch o
            const float ewc = __uint_as_float(pr & 0xffff0000u);  // ch o+64
            const float pnf = __uint_as_float(pnv[i] << 16);
            const float pnc = __uint_as_float(pnv[i] & 0xffff0000u);
            const float gf = ewf + psf + pnf;
            const float gc = ewc + psc + pnc;
            if (MODE == 0) {
                sA += gf; qA = fmaf(gf, gf, qA);
                sB += gc; qB = fmaf(gc, gc, qB);
            } else {
                const float xf = fmaf(gf, s1f, h1f);
                const float xc = fmaf(gc, s1c, h1c);
                const float filt = 1.0f / (1.0f + __expf(-xf));
                accm = fmaf(filt, softplusf(xc), accm);
                if (m == 11) {
                    const int n = nbase + g / 12;
                    nsum[(size_t)n * AF + o] = accm;
                    sB += accm; qB = fmaf(accm, accm, qB);
                }
            }
        }
        __syncthreads();   // reads done before next tile's writes clobber
    }

    // ---- cross-wave reduction -> per-block partials
    if (MODE == 0) {
        red[w][0 * 64 + lane] = sA;
        red[w][1 * 64 + lane] = qA;
        red[w][2 * 64 + lane] = sB;
        red[w][3 * 64 + lane] = qB;
        __syncthreads();
        const int s = threadIdx.x;            // 0..255
        const int oc = (s & 127) >> 1;
        const int v  = (s >> 7) * 2 + (s & 1);
        const int mp = v * 64 + oc;
        partial[(size_t)blockIdx.x * 256 + s] =
            red[0][mp] + red[1][mp] + red[2][mp] + red[3][mp];
    } else {
        red[w][0 * 64 + lane] = sB;
        red[w][1 * 64 + lane] = qB;
        __syncthreads();
        const int s = threadIdx.x;
        if (s < 128) {
            const int oc = s >> 1;
            const int v  = s & 1;
            const int mp = v * 64 + oc;
            partial[(size_t)blockIdx.x * 128 + s] =
                red[0][mp] + red[1][mp] + red[2][mp] + red[3][mp];
        }
    }
}

// ---------------------------------------------------------------------------
// Reduce per-block partials [NB][2*nch] -> scale/shift per channel.
__global__ __launch_bounds__(256) void k_bn_fin(
    const float* __restrict__ partial, const float* __restrict__ gamma,
    const float* __restrict__ beta, float* __restrict__ coef,
    int nch, int NB, float invR)
{
    const int c = blockIdx.x;
    const int tid = threadIdx.x;
    float s = 0.f, qq = 0.f;
    for (int i = tid; i < NB; i += 256) {
        const float* pp = partial + (size_t)i * (2 * nch) + 2 * c;
        s += pp[0]; qq += pp[1];
    }
    __shared__ float ls[256], lq[256];
    ls[tid] = s; lq[tid] = qq;
    __syncthreads();
    for (int off = 128; off > 0; off >>= 1) {
        if (tid < off) { ls[tid] += ls[tid + off]; lq[tid] += lq[tid + off]; }
        __syncthreads();
    }
    if (tid == 0) {
        float mean = ls[0] * invR;
        float var  = fmaxf(lq[0] * invR - mean * mean, 0.f);
        float sc = gamma[c] * rsqrtf(var + BN_EPS);
        coef[c]       = sc;
        coef[nch + c] = beta[c] - mean * sc;
    }
}

// ---------------------------------------------------------------------------
// K6: out = softplus(atom_in + BN2(nbr_sumed))
__global__ __launch_bounds__(256) void k_final(
    const float* __restrict__ atom_in, const float* __restrict__ nsum,
    const float* __restrict__ bn2, float* __restrict__ out, int total)
{
    int i = blockIdx.x * 256 + threadIdx.x;
    if (i >= total) return;
    int f = i & (AF - 1);
    float v = fmaf(nsum[i], bn2[f], bn2[AF + f]);
    float x = atom_in[i] + v;
    out[i] = softplusf(x);
}

// ---------------------------------------------------------------------------
extern "C" void kernel_launch(void* const* d_in, const int* in_sizes, int n_in,
                              void* d_out, int out_size, void* d_ws, size_t ws_size,
                              hipStream_t stream)
{
    const float* atom_in = (const float*)d_in[0];
    const float* nbr_fea = (const float*)d_in[1];
    const int*   nbr_idx = (const int*)d_in[2];
    const float* fc_w    = (const float*)d_in[3];
    const float* fc_b    = (const float*)d_in[4];
    const float* g1      = (const float*)d_in[5];
    const float* b1      = (const float*)d_in[6];
    const float* g2      = (const float*)d_in[7];
    const float* b2      = (const float*)d_in[8];
    float* out = (float*)d_out;

    const int N = in_sizes[0] / AF;       // 100000 (N % 32 == 0)
    const int conv_blocks = N / 32;       // 3125
    const int NB = conv_blocks;           // per-block partial rows

    // ws budget: ~78.45 MB (< 83.09 MB proven safe in round 2).
    // p1 aliases nsum (disjoint lifetimes).
    char* ws = (char*)d_ws;
    size_t off = 0;
    uint16_t* wp_proj = (uint16_t*)(ws + off); off += 16384 * 2;
    uint16_t* wp_edge = (uint16_t*)(ws + off); off += 8192 * 2;
    uint16_t* Ps = (uint16_t*)(ws + off); off += (size_t)N * 128 * 2;  // 25.6MB
    uint16_t* Pn = (uint16_t*)(ws + off); off += (size_t)N * 128 * 2;  // 25.6MB
    float* bn1  = (float*)(ws + off);  off += 256 * 4;
    float* bn2c = (float*)(ws + off);  off += 128 * 4;
    off = (off + 511) & ~(size_t)511;
    float* nsum = (float*)(ws + off);
    float* p1   = nsum;                       // alias, 3.2MB < 25.6MB
    off += (size_t)N * AF * 4;
    float* p2   = (float*)(ws + off);  off += (size_t)NB * 128 * 4;

    k_prep<<<96, 256, 0, stream>>>(fc_w, wp_proj, wp_edge);
    k_proj<<<(N + 63) / 64, 256, 0, stream>>>(atom_in, wp_proj, fc_b, Ps, Pn, N);
    k_conv<0><<<conv_blocks, 256, 0, stream>>>((const uint32_t*)Ps,
                                               (const uint32_t*)Pn,
                                               nbr_fea, nbr_idx, wp_edge,
                                               nullptr, p1, nullptr, N);
    k_bn_fin<<<128, 256, 0, stream>>>(p1, g1, b1, bn1, 128, NB,
                                      1.0f / (float)(N * MNBR));
    k_conv<1><<<conv_blocks, 256, 0, stream>>>((const uint32_t*)Ps,
                                               (const uint32_t*)Pn,
                                               nbr_fea, nbr_idx, wp_edge,
                                               bn1, p2, nsum, N);
    k_bn_fin<<<64, 256, 0, stream>>>(p2, g2, b2, bn2c, 64, NB, 1.0f / (float)N);

    const int total = N * AF;
    k_final<<<(total + 255) / 256, 256, 0, stream>>>(atom_in, nsum, bn2c, out,
                                                     total);
}

// Round 3
// 805.477 us; speedup vs baseline: 1.0032x; 1.0032x over previous
//
#include <hip/hip_runtime.h>
#include <stdint.h>

typedef __attribute__((ext_vector_type(8))) short bf16x8;
typedef __attribute__((ext_vector_type(4))) float f32x4;

static constexpr int MNBR   = 12;
static constexpr int AF     = 64;     // atom feature dim
static constexpr int EF     = 41;     // edge feature dim
static constexpr int IN_DIM = 2 * AF + EF;   // 169
static constexpr float BN_EPS = 1e-5f;

// LDS EW tile: 16 rows x 128 ch, row stride 132 u16 (=66 dwords, breaks
// power-of-2 bank strides; all access 2-way conflict max = free)
static constexpr int EW_ROW_U16 = 132;

__device__ __forceinline__ uint16_t f2bfbits(float f) {
    uint32_t x = __float_as_uint(f);
    uint32_t r = x + 0x7fffu + ((x >> 16) & 1u);  // RNE
    return (uint16_t)(r >> 16);
}
__device__ __forceinline__ float softplusf(float x) {
    return fmaxf(x, 0.f) + __logf(1.0f + __expf(-fabsf(x)));
}

// ---------------------------------------------------------------------------
// K0: repack fc_w (fp32) into bf16 MFMA B-fragment order.
// B frag for 16x16x32: lane holds B[k = s*32 + (lane>>4)*8 + j][n = lane&15].
__global__ __launch_bounds__(256) void k_prep(
    const float* __restrict__ fc_w, uint16_t* __restrict__ wp_proj,
    uint16_t* __restrict__ wp_edge)
{
    int e = blockIdx.x * 256 + threadIdx.x;
    if (e < 16384) {
        int j = e & 7, lane = (e >> 3) & 63, s = (e >> 9) & 1, t = e >> 10;
        int n = lane & 15, q = lane >> 4;
        int k = s * 32 + q * 8 + j;
        int c = t * 16 + n;
        float v = (c < 128) ? fc_w[c * IN_DIM + k]
                            : fc_w[(c - 128) * IN_DIM + 64 + k];
        wp_proj[e] = f2bfbits(v);
    } else if (e < 24576) {
        int e2 = e - 16384;
        int j = e2 & 7, lane = (e2 >> 3) & 63, s = (e2 >> 9) & 1, t = e2 >> 10;
        int n = lane & 15, q = lane >> 4;
        int k = s * 32 + q * 8 + j;
        int o = t * 16 + n;
        wp_edge[e2] = (k < EF) ? f2bfbits(fc_w[o * IN_DIM + 2 * AF + k])
                               : (uint16_t)0;
    }
}

// ---------------------------------------------------------------------------
// K1 (MFMA): projection GEMM. Output is PAIR-INTERLEAVED:
//   Ps[n][o] u32 = { lo: self ch o (+bias[o]), hi: self ch 64+o (+bias[64+o]) }
//   Pn[n][o] u32 = { lo: nbr  ch o,            hi: nbr  ch 64+o }
// so the conv epilogue gathers ONE dword per edge per lane.
__global__ __launch_bounds__(256) void k_proj(
    const float* __restrict__ atom_in, const uint16_t* __restrict__ wp_proj,
    const float* __restrict__ fc_b, uint16_t* __restrict__ Ps,
    uint16_t* __restrict__ Pn, int N)
{
    const int lane = threadIdx.x & 63;
    const int w    = __builtin_amdgcn_readfirstlane((int)(threadIdx.x >> 6));
    const int a0   = blockIdx.x * 64 + w * 16;
    const int mrow = lane & 15, q = lane >> 4;
    const int arow = a0 + mrow;

    bf16x8 A0 = {}, A1 = {};
    if (arow < N) {
        const float* pa = atom_in + (size_t)arow * AF;
#pragma unroll
        for (int j = 0; j < 8; ++j) {
            A0[j] = (short)f2bfbits(pa[q * 8 + j]);       // k = q*8+j
            A1[j] = (short)f2bfbits(pa[32 + q * 8 + j]);  // k = 32+q*8+j
        }
    }

    const bf16x8* wp = (const bf16x8*)wp_proj;
#pragma unroll
    for (int t = 0; t < 16; ++t) {
        f32x4 acc = {0.f, 0.f, 0.f, 0.f};
        bf16x8 b0 = wp[(t * 2 + 0) * 64 + lane];
        bf16x8 b1 = wp[(t * 2 + 1) * 64 + lane];
        acc = __builtin_amdgcn_mfma_f32_16x16x32_bf16(A0, b0, acc, 0, 0, 0);
        acc = __builtin_amdgcn_mfma_f32_16x16x32_bf16(A1, b1, acc, 0, 0, 0);
        const int c = t * 16 + (lane & 15);               // C col = channel
        const float bias = (c < 128) ? fc_b[c] : 0.f;
#pragma unroll
        for (int r = 0; r < 4; ++r) {
            const int row = q * 4 + r;                    // C row = atom
            const int atom = a0 + row;
            if (atom < N) {
                const uint16_t v = f2bfbits(acc[r] + bias);
                const size_t base = (size_t)atom * 128;
                if (c < 64)       Ps[base + 2 * c] = v;
                else if (c < 128) Ps[base + 2 * (c - 64) + 1] = v;
                else if (c < 192) Pn[base + 2 * (c - 128)] = v;
                else              Pn[base + 2 * (c - 192) + 1] = v;
            }
        }
    }
}

// ---------------------------------------------------------------------------
// K2/K4: fused conv pass. Block = 384 edge rows = 32 atoms. Wave = 96 rows.
// Round-3 fixes (vs round-2 residual scratch):
//  * pnv[16] alloca -> 16 NAMED scalars via macro expansion. SROA runs
//    before loop unrolling, so ANY array indexed by a loop var goes to
//    scratch (that was the 440MB WRITE_SIZE). Named scalars can't.
//  * issue order: edge-row loads FIRST, then self-pairs, then the 16
//    gathers. vmcnt is ordered oldest-first, so the A-fragment wait is a
//    counted vmcnt that leaves the gathers in flight under the GEMM; the
//    pre-epilogue barrier drain is where they must land anyway.
//  * edge rows loaded as named f32x4 (memcpy -> dwordx4, no arrays).
template <int MODE>
__global__ __launch_bounds__(256, 3) void k_conv(
    const uint32_t* __restrict__ Ps32, const uint32_t* __restrict__ Pn32,
    const float* __restrict__ nbr, const int* __restrict__ idx,
    const uint16_t* __restrict__ wp_edge, const float* __restrict__ bn1coef,
    float* __restrict__ partial, float* __restrict__ nsum, int N)
{
    __shared__ uint16_t ew16[4][16 * EW_ROW_U16];
    __shared__ float red[4][256];
    __shared__ uint16_t bsh[8192];          // staged wp_edge (16 KB)

    const int tid  = threadIdx.x;
    const int lane = tid & 63;
    const int w    = __builtin_amdgcn_readfirstlane((int)(tid >> 6));
    const int col  = lane & 15, q = lane >> 4;
    const int o    = lane;                  // epilogue channel pair (o, o+64)
    (void)N;

    const int rbase = blockIdx.x * 384 + w * 96;   // divisible by 12
    const int nbase = rbase / 12;

    // ---- preload neighbor indices for this wave's 96 rows (2 VGPRs)
    int idxA = idx[rbase + lane];
    int idxB = 0;
    if (lane < 32) idxB = idx[rbase + 64 + lane];

    // ---- stage edge-weight B fragments into LDS (shared by all 4 waves)
    {
        const uint4* s4 = (const uint4*)wp_edge;
        uint4* d4 = (uint4*)bsh;
#pragma unroll
        for (int k = 0; k < 4; ++k) d4[k * 256 + tid] = s4[k * 256 + tid];
    }

    float s1f = 0.f, h1f = 0.f, s1c = 0.f, h1c = 0.f;
    if (MODE == 1) {
        s1f = bn1coef[o];       h1f = bn1coef[128 + o];
        s1c = bn1coef[64 + o];  h1c = bn1coef[192 + o];
    }

    float sA = 0.f, qA = 0.f, sB = 0.f, qB = 0.f;
    float accm = 0.f, psf = 0.f, psc = 0.f;
    uint16_t* myew = ew16[w];
    const bf16x8* bvs = (const bf16x8*)bsh;

    __syncthreads();   // bsh staged before first GEMM use

#pragma unroll
    for (int mt = 0; mt < 6; ++mt) {
        const int rs = rbase + mt * 16;

        // ---- edge-row loads FIRST (oldest in the vmcnt queue): named f32x4
        const float* er = nbr + (size_t)(rs + col) * EF;
        f32x4 e0, e1, e2 = {0.f, 0.f, 0.f, 0.f}, e3 = {0.f, 0.f, 0.f, 0.f};
        float e4 = 0.f;
        __builtin_memcpy(&e0, er + q * 8, 16);
        __builtin_memcpy(&e1, er + q * 8 + 4, 16);
        if (q == 0) {
            __builtin_memcpy(&e2, er + 32, 16);
            __builtin_memcpy(&e3, er + 36, 16);
        } else if (q == 1) {
            e4 = er[40];
        }

        // ---- pre-issue the (<=2) self-pair loads whose m==0 row is in this
        // tile. Named regs, uniform guards.
        const int aA = (mt * 16 + 11) / 12;     // first atom starting in tile
        const int gA = aA * 12;
        const int gB = gA + 12;
        uint32_t psA = 0u, psB = 0u;
        if (gA < mt * 16 + 16) psA = Ps32[(size_t)(nbase + aA) * 64 + o];
        if (gB < mt * 16 + 16) psB = Ps32[(size_t)(nbase + aA + 1) * 64 + o];
        bool useB = false;

        // ---- issue this tile's 16 neighbor gathers into NAMED scalars.
        // Consumed only after the barrier; in flight under the GEMM.
        uint32_t pn0, pn1, pn2, pn3, pn4, pn5, pn6, pn7;
        uint32_t pn8, pn9, pn10, pn11, pn12, pn13, pn14, pn15;
#define GATH(i)                                                               \
        {                                                                     \
            const int g_ = mt * 16 + (i);                                     \
            const int j_ = (g_ < 64)                                          \
                ? __builtin_amdgcn_readlane(idxA, g_)                         \
                : __builtin_amdgcn_readlane(idxB, g_ - 64);                   \
            pn##i = Pn32[(size_t)j_ * 64 + o];                                \
        }
        GATH(0)  GATH(1)  GATH(2)  GATH(3)
        GATH(4)  GATH(5)  GATH(6)  GATH(7)
        GATH(8)  GATH(9)  GATH(10) GATH(11)
        GATH(12) GATH(13) GATH(14) GATH(15)
#undef GATH

        // ---- A fragments: fp32 edge row -> bf16 (waits only the e-loads,
        // counted vmcnt; gathers stay outstanding)
        bf16x8 A0, A1 = {};
#pragma unroll
        for (int j = 0; j < 4; ++j) {
            A0[j]     = (short)f2bfbits(e0[j]);
            A0[4 + j] = (short)f2bfbits(e1[j]);
        }
        if (q == 0) {
#pragma unroll
            for (int j = 0; j < 4; ++j) {
                A1[j]     = (short)f2bfbits(e2[j]);
                A1[4 + j] = (short)f2bfbits(e3[j]);
            }
        } else if (q == 1) {
            A1[0] = (short)f2bfbits(e4);
        }

        // ---- edge GEMM: 8 N-tiles, B from LDS
        f32x4 acc[8];
#pragma unroll
        for (int t = 0; t < 8; ++t) {
            bf16x8 b0 = bvs[(t * 2 + 0) * 64 + lane];
            bf16x8 b1 = bvs[(t * 2 + 1) * 64 + lane];
            f32x4 a = {0.f, 0.f, 0.f, 0.f};
            a = __builtin_amdgcn_mfma_f32_16x16x32_bf16(A0, b0, a, 0, 0, 0);
            a = __builtin_amdgcn_mfma_f32_16x16x32_bf16(A1, b1, a, 0, 0, 0);
            acc[t] = a;
        }

        // ---- C -> LDS, interleaved: ch<64 at even u16, ch>=64 at odd u16
#pragma unroll
        for (int t = 0; t < 8; ++t) {
            const int ch  = t * 16 + col;
            const int pos = (ch < 64) ? (ch * 2) : ((ch - 64) * 2 + 1);
#pragma unroll
            for (int r = 0; r < 4; ++r) {
                const int row = q * 4 + r;
                myew[row * EW_ROW_U16 + pos] = f2bfbits(acc[t][r]);
            }
        }
        __syncthreads();   // writes (all lanes) visible before cross-lane reads

        // ---- epilogue: 16 rows, lane o handles channels (o, o+64)
#define EPI(i, PN)                                                            \
        {                                                                     \
            const int g_ = mt * 16 + (i);                                     \
            const int m_ = g_ % 12;                                           \
            if (m_ == 0) {                                                    \
                const uint32_t pp_ = useB ? psB : psA;                        \
                useB = true;                                                  \
                psf  = __uint_as_float(pp_ << 16);                            \
                psc  = __uint_as_float(pp_ & 0xffff0000u);                    \
                accm = 0.f;                                                   \
            }                                                                 \
            uint32_t pr_;                                                     \
            __builtin_memcpy(&pr_, &myew[(i) * EW_ROW_U16 + 2 * o], 4);       \
            const float ewf = __uint_as_float(pr_ << 16);                     \
            const float ewc = __uint_as_float(pr_ & 0xffff0000u);             \
            const float pnf = __uint_as_float((PN) << 16);                    \
            const float pnc = __uint_as_float((PN) & 0xffff0000u);            \
            const float gf = ewf + psf + pnf;                                 \
            const float gc = ewc + psc + pnc;                                 \
            if (MODE == 0) {                                                  \
                sA += gf; qA = fmaf(gf, gf, qA);                              \
                sB += gc; qB = fmaf(gc, gc, qB);                              \
            } else {                                                          \
                const float xf = fmaf(gf, s1f, h1f);                          \
                const float xc = fmaf(gc, s1c, h1c);                          \
                const float filt = 1.0f / (1.0f + __expf(-xf));               \
                accm = fmaf(filt, softplusf(xc), accm);                       \
                if (m_ == 11) {                                               \
                    const int n_ = nbase + g_ / 12;                           \
                    nsum[(size_t)n_ * AF + o] = accm;                         \
                    sB += accm; qB = fmaf(accm, accm, qB);                    \
                }                                                             \
            }                                                                 \
        }
        EPI(0, pn0)   EPI(1, pn1)   EPI(2, pn2)   EPI(3, pn3)
        EPI(4, pn4)   EPI(5, pn5)   EPI(6, pn6)   EPI(7, pn7)
        EPI(8, pn8)   EPI(9, pn9)   EPI(10, pn10) EPI(11, pn11)
        EPI(12, pn12) EPI(13, pn13) EPI(14, pn14) EPI(15, pn15)
#undef EPI
        __syncthreads();   // reads done before next tile's writes clobber
    }

    // ---- cross-wave reduction -> per-block partials
    if (MODE == 0) {
        red[w][0 * 64 + lane] = sA;
        red[w][1 * 64 + lane] = qA;
        red[w][2 * 64 + lane] = sB;
        red[w][3 * 64 + lane] = qB;
        __syncthreads();
        const int s = threadIdx.x;            // 0..255
        const int oc = (s & 127) >> 1;
        const int v  = (s >> 7) * 2 + (s & 1);
        const int mp = v * 64 + oc;
        partial[(size_t)blockIdx.x * 256 + s] =
            red[0][mp] + red[1][mp] + red[2][mp] + red[3][mp];
    } else {
        red[w][0 * 64 + lane] = sB;
        red[w][1 * 64 + lane] = qB;
        __syncthreads();
        const int s = threadIdx.x;
        if (s < 128) {
            const int oc = s >> 1;
            const int v  = s & 1;
            const int mp = v * 64 + oc;
            partial[(size_t)blockIdx.x * 128 + s] =
                red[0][mp] + red[1][mp] + red[2][mp] + red[3][mp];
        }
    }
}

// ---------------------------------------------------------------------------
// Reduce per-block partials [NB][2*nch] -> scale/shift per channel.
__global__ __launch_bounds__(256) void k_bn_fin(
    const float* __restrict__ partial, const float* __restrict__ gamma,
    const float* __restrict__ beta, float* __restrict__ coef,
    int nch, int NB, float invR)
{
    const int c = blockIdx.x;
    const int tid = threadIdx.x;
    float s = 0.f, qq = 0.f;
    for (int i = tid; i < NB; i += 256) {
        const float* pp = partial + (size_t)i * (2 * nch) + 2 * c;
        s += pp[0]; qq += pp[1];
    }
    __shared__ float ls[256], lq[256];
    ls[tid] = s; lq[tid] = qq;
    __syncthreads();
    for (int off = 128; off > 0; off >>= 1) {
        if (tid < off) { ls[tid] += ls[tid + off]; lq[tid] += lq[tid + off]; }
        __syncthreads();
    }
    if (tid == 0) {
        float mean = ls[0] * invR;
        float var  = fmaxf(lq[0] * invR - mean * mean, 0.f);
        float sc = gamma[c] * rsqrtf(var + BN_EPS);
        coef[c]       = sc;
        coef[nch + c] = beta[c] - mean * sc;
    }
}

// ---------------------------------------------------------------------------
// K6: out = softplus(atom_in + BN2(nbr_sumed))
__global__ __launch_bounds__(256) void k_final(
    const float* __restrict__ atom_in, const float* __restrict__ nsum,
    const float* __restrict__ bn2, float* __restrict__ out, int total)
{
    int i = blockIdx.x * 256 + threadIdx.x;
    if (i >= total) return;
    int f = i & (AF - 1);
    float v = fmaf(nsum[i], bn2[f], bn2[AF + f]);
    float x = atom_in[i] + v;
    out[i] = softplusf(x);
}

// ---------------------------------------------------------------------------
extern "C" void kernel_launch(void* const* d_in, const int* in_sizes, int n_in,
                              void* d_out, int out_size, void* d_ws, size_t ws_size,
                              hipStream_t stream)
{
    const float* atom_in = (const float*)d_in[0];
    const float* nbr_fea = (const float*)d_in[1];
    const int*   nbr_idx = (const int*)d_in[2];
    const float* fc_w    = (const float*)d_in[3];
    const float* fc_b    = (const float*)d_in[4];
    const float* g1      = (const float*)d_in[5];
    const float* b1      = (const float*)d_in[6];
    const float* g2      = (const float*)d_in[7];
    const float* b2      = (const float*)d_in[8];
    float* out = (float*)d_out;

    const int N = in_sizes[0] / AF;       // 100000 (N % 32 == 0)
    const int conv_blocks = N / 32;       // 3125
    const int NB = conv_blocks;           // per-block partial rows

    // ws budget: ~78.45 MB (< 83.09 MB proven safe in round 2).
    // p1 aliases nsum (disjoint lifetimes).
    char* ws = (char*)d_ws;
    size_t off = 0;
    uint16_t* wp_proj = (uint16_t*)(ws + off); off += 16384 * 2;
    uint16_t* wp_edge = (uint16_t*)(ws + off); off += 8192 * 2;
    uint16_t* Ps = (uint16_t*)(ws + off); off += (size_t)N * 128 * 2;  // 25.6MB
    uint16_t* Pn = (uint16_t*)(ws + off); off += (size_t)N * 128 * 2;  // 25.6MB
    float* bn1  = (float*)(ws + off);  off += 256 * 4;
    float* bn2c = (float*)(ws + off);  off += 128 * 4;
    off = (off + 511) & ~(size_t)511;
    float* nsum = (float*)(ws + off);
    float* p1   = nsum;                       // alias, 3.2MB < 25.6MB
    off += (size_t)N * AF * 4;
    float* p2   = (float*)(ws + off);  off += (size_t)NB * 128 * 4;

    k_prep<<<96, 256, 0, stream>>>(fc_w, wp_proj, wp_edge);
    k_proj<<<(N + 63) / 64, 256, 0, stream>>>(atom_in, wp_proj, fc_b, Ps, Pn, N);
    k_conv<0><<<conv_blocks, 256, 0, stream>>>((const uint32_t*)Ps,
                                               (const uint32_t*)Pn,
                                               nbr_fea, nbr_idx, wp_edge,
                                               nullptr, p1, nullptr, N);
    k_bn_fin<<<128, 256, 0, stream>>>(p1, g1, b1, bn1, 128, NB,
                                      1.0f / (float)(N * MNBR));
    k_conv<1><<<conv_blocks, 256, 0, stream>>>((const uint32_t*)Ps,
                                               (const uint32_t*)Pn,
                                               nbr_fea, nbr_idx, wp_edge,
                                               bn1, p2, nsum, N);
    k_bn_fin<<<64, 256, 0, stream>>>(p2, g2, b2, bn2c, 64, NB, 1.0f / (float)N);

    const int total = N * AF;
    k_final<<<(total + 255) / 256, 256, 0, stream>>>(atom_in, nsum, bn2c, out,
                                                     total);
}

// Round 4
// 615.735 us; speedup vs baseline: 1.3124x; 1.3082x over previous
//
#include <hip/hip_runtime.h>
#include <stdint.h>

typedef __attribute__((ext_vector_type(8))) short bf16x8;
typedef __attribute__((ext_vector_type(4))) float f32x4;

static constexpr int MNBR   = 12;
static constexpr int AF     = 64;     // atom feature dim
static constexpr int EF     = 41;     // edge feature dim
static constexpr int IN_DIM = 2 * AF + EF;   // 169
static constexpr float BN_EPS = 1e-5f;

// LDS EW tile: 16 rows x 128 ch, row stride 132 u16 (=66 dwords, breaks
// power-of-2 bank strides; all access 2-way conflict max = free)
static constexpr int EW_ROW_U16 = 132;

__device__ __forceinline__ uint16_t f2bfbits(float f) {
    uint32_t x = __float_as_uint(f);
    uint32_t r = x + 0x7fffu + ((x >> 16) & 1u);  // RNE
    return (uint16_t)(r >> 16);
}
__device__ __forceinline__ float softplusf(float x) {
    return fmaxf(x, 0.f) + __logf(1.0f + __expf(-fabsf(x)));
}

// ---------------------------------------------------------------------------
// K0: repack fc_w (fp32) into bf16 MFMA B-fragment order.
// B frag for 16x16x32: lane holds B[k = s*32 + (lane>>4)*8 + j][n = lane&15].
__global__ __launch_bounds__(256) void k_prep(
    const float* __restrict__ fc_w, uint16_t* __restrict__ wp_proj,
    uint16_t* __restrict__ wp_edge)
{
    int e = blockIdx.x * 256 + threadIdx.x;
    if (e < 16384) {
        int j = e & 7, lane = (e >> 3) & 63, s = (e >> 9) & 1, t = e >> 10;
        int n = lane & 15, q = lane >> 4;
        int k = s * 32 + q * 8 + j;
        int c = t * 16 + n;
        float v = (c < 128) ? fc_w[c * IN_DIM + k]
                            : fc_w[(c - 128) * IN_DIM + 64 + k];
        wp_proj[e] = f2bfbits(v);
    } else if (e < 24576) {
        int e2 = e - 16384;
        int j = e2 & 7, lane = (e2 >> 3) & 63, s = (e2 >> 9) & 1, t = e2 >> 10;
        int n = lane & 15, q = lane >> 4;
        int k = s * 32 + q * 8 + j;
        int o = t * 16 + n;
        wp_edge[e2] = (k < EF) ? f2bfbits(fc_w[o * IN_DIM + 2 * AF + k])
                               : (uint16_t)0;
    }
}

// ---------------------------------------------------------------------------
// K1 (MFMA): projection GEMM. Output is PAIR-INTERLEAVED:
//   Ps[n][o] u32 = { lo: self ch o (+bias[o]), hi: self ch 64+o (+bias[64+o]) }
//   Pn[n][o] u32 = { lo: nbr  ch o,            hi: nbr  ch 64+o }
// so the conv epilogue gathers ONE dword per edge per lane.
__global__ __launch_bounds__(256) void k_proj(
    const float* __restrict__ atom_in, const uint16_t* __restrict__ wp_proj,
    const float* __restrict__ fc_b, uint16_t* __restrict__ Ps,
    uint16_t* __restrict__ Pn, int N)
{
    const int lane = threadIdx.x & 63;
    const int w    = __builtin_amdgcn_readfirstlane((int)(threadIdx.x >> 6));
    const int a0   = blockIdx.x * 64 + w * 16;
    const int mrow = lane & 15, q = lane >> 4;
    const int arow = a0 + mrow;

    bf16x8 A0 = {}, A1 = {};
    if (arow < N) {
        const float* pa = atom_in + (size_t)arow * AF;
#pragma unroll
        for (int j = 0; j < 8; ++j) {
            A0[j] = (short)f2bfbits(pa[q * 8 + j]);       // k = q*8+j
            A1[j] = (short)f2bfbits(pa[32 + q * 8 + j]);  // k = 32+q*8+j
        }
    }

    const bf16x8* wp = (const bf16x8*)wp_proj;
#pragma unroll
    for (int t = 0; t < 16; ++t) {
        f32x4 acc = {0.f, 0.f, 0.f, 0.f};
        bf16x8 b0 = wp[(t * 2 + 0) * 64 + lane];
        bf16x8 b1 = wp[(t * 2 + 1) * 64 + lane];
        acc = __builtin_amdgcn_mfma_f32_16x16x32_bf16(A0, b0, acc, 0, 0, 0);
        acc = __builtin_amdgcn_mfma_f32_16x16x32_bf16(A1, b1, acc, 0, 0, 0);
        const int c = t * 16 + (lane & 15);               // C col = channel
        const float bias = (c < 128) ? fc_b[c] : 0.f;
#pragma unroll
        for (int r = 0; r < 4; ++r) {
            const int row = q * 4 + r;                    // C row = atom
            const int atom = a0 + row;
            if (atom < N) {
                const uint16_t v = f2bfbits(acc[r] + bias);
                const size_t base = (size_t)atom * 128;
                if (c < 64)       Ps[base + 2 * c] = v;
                else if (c < 128) Ps[base + 2 * (c - 64) + 1] = v;
                else if (c < 192) Pn[base + 2 * (c - 128)] = v;
                else              Pn[base + 2 * (c - 192) + 1] = v;
            }
        }
    }
}

// ---------------------------------------------------------------------------
// K2/K4: fused conv pass. Block = 384 edge rows = 32 atoms. Wave = 96 rows.
// Round-4 fix: __launch_bounds__(256) with NO min-occupancy arg.
// (256,3) pinned the allocator to 84 VGPRs in rounds 1-3 — identical VGPR
// count across three different bodies — forcing ~520 B/thread of spill
// (416 MB WRITE_SIZE vs ~3 MB legit, +270 MB spill re-reads in FETCH).
// Round 0 at plain (256) allocated 188 VGPRs with 3 MB writes. Let the
// allocator use what it needs; B-in-LDS already cut natural pressure.
template <int MODE>
__global__ __launch_bounds__(256) void k_conv(
    const uint32_t* __restrict__ Ps32, const uint32_t* __restrict__ Pn32,
    const float* __restrict__ nbr, const int* __restrict__ idx,
    const uint16_t* __restrict__ wp_edge, const float* __restrict__ bn1coef,
    float* __restrict__ partial, float* __restrict__ nsum, int N)
{
    __shared__ uint16_t ew16[4][16 * EW_ROW_U16];
    __shared__ float red[4][256];
    __shared__ uint16_t bsh[8192];          // staged wp_edge (16 KB)

    const int tid  = threadIdx.x;
    const int lane = tid & 63;
    const int w    = __builtin_amdgcn_readfirstlane((int)(tid >> 6));
    const int col  = lane & 15, q = lane >> 4;
    const int o    = lane;                  // epilogue channel pair (o, o+64)
    (void)N;

    const int rbase = blockIdx.x * 384 + w * 96;   // divisible by 12
    const int nbase = rbase / 12;

    // ---- preload neighbor indices for this wave's 96 rows (2 VGPRs)
    int idxA = idx[rbase + lane];
    int idxB = 0;
    if (lane < 32) idxB = idx[rbase + 64 + lane];

    // ---- stage edge-weight B fragments into LDS (shared by all 4 waves)
    {
        const uint4* s4 = (const uint4*)wp_edge;
        uint4* d4 = (uint4*)bsh;
#pragma unroll
        for (int k = 0; k < 4; ++k) d4[k * 256 + tid] = s4[k * 256 + tid];
    }

    float s1f = 0.f, h1f = 0.f, s1c = 0.f, h1c = 0.f;
    if (MODE == 1) {
        s1f = bn1coef[o];       h1f = bn1coef[128 + o];
        s1c = bn1coef[64 + o];  h1c = bn1coef[192 + o];
    }

    float sA = 0.f, qA = 0.f, sB = 0.f, qB = 0.f;
    float accm = 0.f, psf = 0.f, psc = 0.f;
    uint16_t* myew = ew16[w];
    const bf16x8* bvs = (const bf16x8*)bsh;

    __syncthreads();   // bsh staged before first GEMM use

#pragma unroll
    for (int mt = 0; mt < 6; ++mt) {
        const int rs = rbase + mt * 16;

        // ---- edge-row loads FIRST (oldest in the vmcnt queue): named f32x4
        const float* er = nbr + (size_t)(rs + col) * EF;
        f32x4 e0, e1, e2 = {0.f, 0.f, 0.f, 0.f}, e3 = {0.f, 0.f, 0.f, 0.f};
        float e4 = 0.f;
        __builtin_memcpy(&e0, er + q * 8, 16);
        __builtin_memcpy(&e1, er + q * 8 + 4, 16);
        if (q == 0) {
            __builtin_memcpy(&e2, er + 32, 16);
            __builtin_memcpy(&e3, er + 36, 16);
        } else if (q == 1) {
            e4 = er[40];
        }

        // ---- pre-issue the (<=2) self-pair loads whose m==0 row is in this
        // tile. Named regs, uniform guards.
        const int aA = (mt * 16 + 11) / 12;     // first atom starting in tile
        const int gA = aA * 12;
        const int gB = gA + 12;
        uint32_t psA = 0u, psB = 0u;
        if (gA < mt * 16 + 16) psA = Ps32[(size_t)(nbase + aA) * 64 + o];
        if (gB < mt * 16 + 16) psB = Ps32[(size_t)(nbase + aA + 1) * 64 + o];
        bool useB = false;

        // ---- issue this tile's 16 neighbor gathers into NAMED scalars.
        // Consumed only after the barrier; in flight under the GEMM.
        uint32_t pn0, pn1, pn2, pn3, pn4, pn5, pn6, pn7;
        uint32_t pn8, pn9, pn10, pn11, pn12, pn13, pn14, pn15;
#define GATH(i)                                                               \
        {                                                                     \
            const int g_ = mt * 16 + (i);                                     \
            const int j_ = (g_ < 64)                                          \
                ? __builtin_amdgcn_readlane(idxA, g_)                         \
                : __builtin_amdgcn_readlane(idxB, g_ - 64);                   \
            pn##i = Pn32[(size_t)j_ * 64 + o];                                \
        }
        GATH(0)  GATH(1)  GATH(2)  GATH(3)
        GATH(4)  GATH(5)  GATH(6)  GATH(7)
        GATH(8)  GATH(9)  GATH(10) GATH(11)
        GATH(12) GATH(13) GATH(14) GATH(15)
#undef GATH

        // ---- A fragments: fp32 edge row -> bf16 (waits only the e-loads,
        // counted vmcnt; gathers stay outstanding)
        bf16x8 A0, A1 = {};
#pragma unroll
        for (int j = 0; j < 4; ++j) {
            A0[j]     = (short)f2bfbits(e0[j]);
            A0[4 + j] = (short)f2bfbits(e1[j]);
        }
        if (q == 0) {
#pragma unroll
            for (int j = 0; j < 4; ++j) {
                A1[j]     = (short)f2bfbits(e2[j]);
                A1[4 + j] = (short)f2bfbits(e3[j]);
            }
        } else if (q == 1) {
            A1[0] = (short)f2bfbits(e4);
        }

        // ---- edge GEMM: 8 N-tiles, B from LDS
        f32x4 acc[8];
#pragma unroll
        for (int t = 0; t < 8; ++t) {
            bf16x8 b0 = bvs[(t * 2 + 0) * 64 + lane];
            bf16x8 b1 = bvs[(t * 2 + 1) * 64 + lane];
            f32x4 a = {0.f, 0.f, 0.f, 0.f};
            a = __builtin_amdgcn_mfma_f32_16x16x32_bf16(A0, b0, a, 0, 0, 0);
            a = __builtin_amdgcn_mfma_f32_16x16x32_bf16(A1, b1, a, 0, 0, 0);
            acc[t] = a;
        }

        // ---- C -> LDS, interleaved: ch<64 at even u16, ch>=64 at odd u16
#pragma unroll
        for (int t = 0; t < 8; ++t) {
            const int ch  = t * 16 + col;
            const int pos = (ch < 64) ? (ch * 2) : ((ch - 64) * 2 + 1);
#pragma unroll
            for (int r = 0; r < 4; ++r) {
                const int row = q * 4 + r;
                myew[row * EW_ROW_U16 + pos] = f2bfbits(acc[t][r]);
            }
        }
        __syncthreads();   // writes (all lanes) visible before cross-lane reads

        // ---- epilogue: 16 rows, lane o handles channels (o, o+64)
#define EPI(i, PN)                                                            \
        {                                                                     \
            const int g_ = mt * 16 + (i);                                     \
            const int m_ = g_ % 12;                                           \
            if (m_ == 0) {                                                    \
                const uint32_t pp_ = useB ? psB : psA;                        \
                useB = true;                                                  \
                psf  = __uint_as_float(pp_ << 16);                            \
                psc  = __uint_as_float(pp_ & 0xffff0000u);                    \
                accm = 0.f;                                                   \
            }                                                                 \
            uint32_t pr_;                                                     \
            __builtin_memcpy(&pr_, &myew[(i) * EW_ROW_U16 + 2 * o], 4);       \
            const float ewf = __uint_as_float(pr_ << 16);                     \
            const float ewc = __uint_as_float(pr_ & 0xffff0000u);             \
            const float pnf = __uint_as_float((PN) << 16);                    \
            const float pnc = __uint_as_float((PN) & 0xffff0000u);            \
            const float gf = ewf + psf + pnf;                                 \
            const float gc = ewc + psc + pnc;                                 \
            if (MODE == 0) {                                                  \
                sA += gf; qA = fmaf(gf, gf, qA);                              \
                sB += gc; qB = fmaf(gc, gc, qB);                              \
            } else {                                                          \
                const float xf = fmaf(gf, s1f, h1f);                          \
                const float xc = fmaf(gc, s1c, h1c);                          \
                const float filt = 1.0f / (1.0f + __expf(-xf));               \
                accm = fmaf(filt, softplusf(xc), accm);                       \
                if (m_ == 11) {                                               \
                    const int n_ = nbase + g_ / 12;                           \
                    nsum[(size_t)n_ * AF + o] = accm;                         \
                    sB += accm; qB = fmaf(accm, accm, qB);                    \
                }                                                             \
            }                                                                 \
        }
        EPI(0, pn0)   EPI(1, pn1)   EPI(2, pn2)   EPI(3, pn3)
        EPI(4, pn4)   EPI(5, pn5)   EPI(6, pn6)   EPI(7, pn7)
        EPI(8, pn8)   EPI(9, pn9)   EPI(10, pn10) EPI(11, pn11)
        EPI(12, pn12) EPI(13, pn13) EPI(14, pn14) EPI(15, pn15)
#undef EPI
        __syncthreads();   // reads done before next tile's writes clobber
    }

    // ---- cross-wave reduction -> per-block partials
    if (MODE == 0) {
        red[w][0 * 64 + lane] = sA;
        red[w][1 * 64 + lane] = qA;
        red[w][2 * 64 + lane] = sB;
        red[w][3 * 64 + lane] = qB;
        __syncthreads();
        const int s = threadIdx.x;            // 0..255
        const int oc = (s & 127) >> 1;
        const int v  = (s >> 7) * 2 + (s & 1);
        const int mp = v * 64 + oc;
        partial[(size_t)blockIdx.x * 256 + s] =
            red[0][mp] + red[1][mp] + red[2][mp] + red[3][mp];
    } else {
        red[w][0 * 64 + lane] = sB;
        red[w][1 * 64 + lane] = qB;
        __syncthreads();
        const int s = threadIdx.x;
        if (s < 128) {
            const int oc = s >> 1;
            const int v  = s & 1;
            const int mp = v * 64 + oc;
            partial[(size_t)blockIdx.x * 128 + s] =
                red[0][mp] + red[1][mp] + red[2][mp] + red[3][mp];
        }
    }
}

// ---------------------------------------------------------------------------
// Reduce per-block partials [NB][2*nch] -> scale/shift per channel.
__global__ __launch_bounds__(256) void k_bn_fin(
    const float* __restrict__ partial, const float* __restrict__ gamma,
    const float* __restrict__ beta, float* __restrict__ coef,
    int nch, int NB, float invR)
{
    const int c = blockIdx.x;
    const int tid = threadIdx.x;
    float s = 0.f, qq = 0.f;
    for (int i = tid; i < NB; i += 256) {
        const float* pp = partial + (size_t)i * (2 * nch) + 2 * c;
        s += pp[0]; qq += pp[1];
    }
    __shared__ float ls[256], lq[256];
    ls[tid] = s; lq[tid] = qq;
    __syncthreads();
    for (int off = 128; off > 0; off >>= 1) {
        if (tid < off) { ls[tid] += ls[tid + off]; lq[tid] += lq[tid + off]; }
        __syncthreads();
    }
    if (tid == 0) {
        float mean = ls[0] * invR;
        float var  = fmaxf(lq[0] * invR - mean * mean, 0.f);
        float sc = gamma[c] * rsqrtf(var + BN_EPS);
        coef[c]       = sc;
        coef[nch + c] = beta[c] - mean * sc;
    }
}

// ---------------------------------------------------------------------------
// K6: out = softplus(atom_in + BN2(nbr_sumed))
__global__ __launch_bounds__(256) void k_final(
    const float* __restrict__ atom_in, const float* __restrict__ nsum,
    const float* __restrict__ bn2, float* __restrict__ out, int total)
{
    int i = blockIdx.x * 256 + threadIdx.x;
    if (i >= total) return;
    int f = i & (AF - 1);
    float v = fmaf(nsum[i], bn2[f], bn2[AF + f]);
    float x = atom_in[i] + v;
    out[i] = softplusf(x);
}

// ---------------------------------------------------------------------------
extern "C" void kernel_launch(void* const* d_in, const int* in_sizes, int n_in,
                              void* d_out, int out_size, void* d_ws, size_t ws_size,
                              hipStream_t stream)
{
    const float* atom_in = (const float*)d_in[0];
    const float* nbr_fea = (const float*)d_in[1];
    const int*   nbr_idx = (const int*)d_in[2];
    const float* fc_w    = (const float*)d_in[3];
    const float* fc_b    = (const float*)d_in[4];
    const float* g1      = (const float*)d_in[5];
    const float* b1      = (const float*)d_in[6];
    const float* g2      = (const float*)d_in[7];
    const float* b2      = (const float*)d_in[8];
    float* out = (float*)d_out;

    const int N = in_sizes[0] / AF;       // 100000 (N % 32 == 0)
    const int conv_blocks = N / 32;       // 3125
    const int NB = conv_blocks;           // per-block partial rows

    // ws budget: ~78.45 MB (< 83.09 MB proven safe in round 2).
    // p1 aliases nsum (disjoint lifetimes).
    char* ws = (char*)d_ws;
    size_t off = 0;
    uint16_t* wp_proj = (uint16_t*)(ws + off); off += 16384 * 2;
    uint16_t* wp_edge = (uint16_t*)(ws + off); off += 8192 * 2;
    uint16_t* Ps = (uint16_t*)(ws + off); off += (size_t)N * 128 * 2;  // 25.6MB
    uint16_t* Pn = (uint16_t*)(ws + off); off += (size_t)N * 128 * 2;  // 25.6MB
    float* bn1  = (float*)(ws + off);  off += 256 * 4;
    float* bn2c = (float*)(ws + off);  off += 128 * 4;
    off = (off + 511) & ~(size_t)511;
    float* nsum = (float*)(ws + off);
    float* p1   = nsum;                       // alias, 3.2MB < 25.6MB
    off += (size_t)N * AF * 4;
    float* p2   = (float*)(ws + off);  off += (size_t)NB * 128 * 4;

    k_prep<<<96, 256, 0, stream>>>(fc_w, wp_proj, wp_edge);
    k_proj<<<(N + 63) / 64, 256, 0, stream>>>(atom_in, wp_proj, fc_b, Ps, Pn, N);
    k_conv<0><<<conv_blocks, 256, 0, stream>>>((const uint32_t*)Ps,
                                               (const uint32_t*)Pn,
                                               nbr_fea, nbr_idx, wp_edge,
                                               nullptr, p1, nullptr, N);
    k_bn_fin<<<128, 256, 0, stream>>>(p1, g1, b1, bn1, 128, NB,
                                      1.0f / (float)(N * MNBR));
    k_conv<1><<<conv_blocks, 256, 0, stream>>>((const uint32_t*)Ps,
                                               (const uint32_t*)Pn,
                                               nbr_fea, nbr_idx, wp_edge,
                                               bn1, p2, nsum, N);
    k_bn_fin<<<64, 256, 0, stream>>>(p2, g2, b2, bn2c, 64, NB, 1.0f / (float)N);

    const int total = N * AF;
    k_final<<<(total + 255) / 256, 256, 0, stream>>>(atom_in, nsum, bn2c, out,
                                                     total);
}